// Round 1
// baseline (433.666 us; speedup 1.0000x reference)
//
#include <hip/hip_runtime.h>
#include <math.h>

// VectorQuantizer on MI355X — round 8: k_score LDS-bandwidth fix.
// latents [64,256,32,32] f32, embedding [1024,256] f32.
// Outputs (concat fp32): quant_st [16777216], loss [1], indices-as-float [65536].
//
// VALIDATED (rounds 2/3/5, absmax 0): numpy index semantics are
//   dist = fl32( fl32(Sx + Ek) - fl32(2*dot) ), argmin first-index ties,
// Sx/Ek = numpy pairwise fp32 (two 128-blocks, 8 accumulators, binary tree),
// dot = sequential ascending-c fp32 FMA chain. MFMA top-2 + margin 3e-4 filter
// + exact re-scan of flagged pixels reproduces it bit-exactly.
//
// ROUND-8 CHANGE (k_score only; numerics bit-identical):
//  * Counters showed LDS-bound: MfmaUtil 19% (MFMA floor 33us of 142us),
//    8.4M bank-conflict cycles, 4 waves re-reading identical B frags.
//  * Dual A-tile: 32 pixels/wave (2x 16x16 A tiles in regs) -> each B read
//    feeds 4 MFMAs (64 FLOP/LDS-byte, was 32). Block=128 pix, grid=512.
//  * B LDS layout octet-major: slot s = dim_octet*32 + code -> wave ds_reads
//    are contiguous (256B per 16-lane phase) -> ~0 bank conflicts.
//  * Staging via __builtin_amdgcn_global_load_lds width=16 (linear dest
//    matches layout) -> no staging VALU/LDS-writes, ONE barrier per chunk.
//  * 32-code chunks (32 iters). Per-pixel MFMA chain order (ks ascending,
//    hi then lo), score formula, ascending-n top-2 updates, butterfly,
//    margin filter: all unchanged -> refine sees identical inputs.
//
// Pipeline:
//  k_prep    : Ek[k]; zero loss + worklist count
//  k_embconv : emb_hi = bf16(emb)
//  k_score   : MFMA bf16-split engine, per-pixel top-2, margin filter
//  k_refine  : 8 pixels/block-group; 32-code LDS tiles; exact fp32 chains
//  k_gather  : gather + straight-through write + fp64 loss partials
//  k_loss    : loss = 1.25 * total / 16777216

#define DIM 256
#define BSTRIDE 262144
#define OUT_LOSS 16777216
#define OUT_IDX  16777217
#define MARGIN_S 3e-4f

#define RG 8          // refine: pixels per group
#define RTILE 32      // refine: codes per LDS tile
#define RSTRIDE 260   // refine: padded row stride (floats); 260%32=4 -> 4-way max

// ws byte offsets (total 1056768 B)
#define WS_LOSS  0
#define WS_COUNT 8
#define WS_ENORM 64
#define WS_EMBH  8192
#define WS_SEL   532480      // 8192 + 1024*256*2
#define WS_WL    794624      // 532480 + 65536*4

typedef __attribute__((ext_vector_type(8))) short short8;
typedef __attribute__((ext_vector_type(4))) float f32x4;

__device__ inline unsigned short f2bf(float f) {   // RNE f32 -> bf16 bits
  unsigned u = __float_as_uint(f);
  unsigned r = 0x7FFFu + ((u >> 16) & 1u);
  return (unsigned short)((u + r) >> 16);
}
__device__ inline float bf2f(unsigned short h) {
  return __uint_as_float(((unsigned)h) << 16);
}

// ---------------- k_prep: numpy-pairwise |e_k|^2, zero loss/count -----------
__global__ void k_prep(const float* __restrict__ emb, float* __restrict__ enormQ,
                       double* __restrict__ lossAcc, int* __restrict__ count) {
  const int k = blockIdx.x * 64 + threadIdx.x;   // 16 blocks x 64
  if (blockIdx.x == 0 && threadIdx.x == 0) { *lossAcc = 0.0; *count = 0; }
  if (k >= 1024) return;
  const float* e = emb + (size_t)k * DIM;
  float blk[2];
  #pragma unroll
  for (int h = 0; h < 2; ++h) {
    const float* a = e + h * 128;
    float r[8];
    #pragma unroll
    for (int j = 0; j < 8; ++j) r[j] = __fmul_rn(a[j], a[j]);
    for (int i = 8; i < 128; i += 8)
      #pragma unroll
      for (int j = 0; j < 8; ++j) r[j] = __fadd_rn(r[j], __fmul_rn(a[i+j], a[i+j]));
    blk[h] = __fadd_rn(__fadd_rn(__fadd_rn(r[0], r[1]), __fadd_rn(r[2], r[3])),
                       __fadd_rn(__fadd_rn(r[4], r[5]), __fadd_rn(r[6], r[7])));
  }
  enormQ[k] = __fadd_rn(blk[0], blk[1]);
}

// ---------------- k_embconv: emb -> bf16 hi ---------------------------------
__global__ void k_embconv(const float* __restrict__ emb, unsigned short* __restrict__ embHi) {
  const int i = (blockIdx.x * 256 + threadIdx.x) * 4;   // 256 blocks x 256
  float4 v = *(const float4*)(emb + i);
  unsigned r0 = (unsigned)f2bf(v.x) | ((unsigned)f2bf(v.y) << 16);
  unsigned r1 = (unsigned)f2bf(v.z) | ((unsigned)f2bf(v.w) << 16);
  uint2 st; st.x = r0; st.y = r1;
  *(uint2*)(embHi + i) = st;
}

// ---------------- k_score: MFMA engine + top-2 filter -----------------------
// 512 blocks x 256 threads (4 waves). Block = 128 pixels; wave = 32 pixels
// (two 16x16 A tiles). Chunk = 32 codes, double-buffered LDS via
// global_load_lds (linear octet-major layout: slot = dim_octet*32 + code).
// MFMA 16x16x32: A[m=lane&15][k=quad*8+j], B[n=lane&15][k=quad*8+j],
//                D[m=quad*4+reg][n=lane&15].
__launch_bounds__(256, 2)
__global__ void k_score(const float* __restrict__ lat,
                        const unsigned short* __restrict__ embHi,
                        const float* __restrict__ enormQ,
                        int* __restrict__ selIdx, float* __restrict__ out,
                        int* __restrict__ count, int* __restrict__ worklist) {
  // 2 bufs x 1024 slots x 8 shorts = 32 KB; slot s=(o*32+n): code n, dims o*8..+7
  __shared__ __align__(16) unsigned short sB[2 * 8192];
  __shared__ float sNorm[1024];                       // 4 KB

  const int t = threadIdx.x;
  const int w = t >> 6;          // wave 0..3
  const int L = t & 63;          // lane
  const int lane15 = L & 15;
  const int quad = L >> 4;

  const int pix0 = blockIdx.x * 128;
  const int bImg = pix0 >> 10;
  const int hw0 = pix0 & 1023;

  // staging source map: wave w issue i covers slots s=(w*4+i)*64+L
  //   o = (w*4+i)*2 + (L>>5), n = L&31 ; LDS dest = bufbase + s*16B (HW linear)
  const int nSrc = L & 31;
  const int oSub = L >> 5;

  // issue chunk-0 staging first so L2 latency hides under A-prep VALU
  #pragma unroll
  for (int i = 0; i < 4; ++i) {
    const int o = (w * 4 + i) * 2 + oSub;
    const unsigned short* src = embHi + ((size_t)nSrc * 256 + o * 8);
    unsigned short* dst = sB + (w * 4 + i) * 512;
    __builtin_amdgcn_global_load_lds(
        (const __attribute__((address_space(1))) unsigned int*)src,
        (__attribute__((address_space(3))) unsigned int*)dst, 16, 0, 0);
  }

  for (int i = t; i < 1024; i += 256) sNorm[i] = enormQ[i];

  // ---- A fragments: 32 pixels of this wave (2 tiles), 8 k-steps, hi+lo ----
  const float* latP0 = lat + (size_t)bImg * BSTRIDE + hw0 + w * 32 + lane15;
  const float* latP1 = latP0 + 16;
  short8 aHi0[8], aLo0[8], aHi1[8], aLo1[8];
  #pragma unroll
  for (int ks = 0; ks < 8; ++ks) {
    #pragma unroll
    for (int j = 0; j < 8; ++j) {
      const size_t off = (size_t)(ks * 32 + quad * 8 + j) * 1024;
      float f0 = latP0[off];
      float f1 = latP1[off];
      unsigned short h0 = f2bf(f0);
      unsigned short h1 = f2bf(f1);
      aHi0[ks][j] = (short)h0; aLo0[ks][j] = (short)f2bf(f0 - bf2f(h0));
      aHi1[ks][j] = (short)h1; aLo1[ks][j] = (short)f2bf(f1 - bf2f(h1));
    }
  }

  // top-2 state: p = tile*4 + r  (tile0 = pixels +0..15, tile1 = +16..31)
  float b1[8], b2[8];
  int i1[8], i2[8];
  #pragma unroll
  for (int p = 0; p < 8; ++p) { b1[p] = INFINITY; b2[p] = INFINITY; i1[p] = 0x7fffffff; i2[p] = 0x7fffffff; }

  __syncthreads();   // drains vmcnt(0): chunk-0 staging complete

  for (int ch = 0; ch < 32; ++ch) {
    const int cur = ch & 1;
    if (ch < 31) {   // prefetch chunk ch+1 into the other buffer
      #pragma unroll
      for (int i = 0; i < 4; ++i) {
        const int o = (w * 4 + i) * 2 + oSub;
        const unsigned short* src = embHi + ((size_t)((ch + 1) * 32 + nSrc) * 256 + o * 8);
        unsigned short* dst = sB + (1 - cur) * 8192 + (w * 4 + i) * 512;
        __builtin_amdgcn_global_load_lds(
            (const __attribute__((address_space(1))) unsigned int*)src,
            (__attribute__((address_space(3))) unsigned int*)dst, 16, 0, 0);
      }
    }
    const unsigned short* bbuf = sB + cur * 8192;
    f32x4 acc0a = {0.f,0.f,0.f,0.f}, acc1a = {0.f,0.f,0.f,0.f};
    f32x4 acc0b = {0.f,0.f,0.f,0.f}, acc1b = {0.f,0.f,0.f,0.f};
    #pragma unroll
    for (int ks = 0; ks < 8; ++ks) {
      const unsigned short* base = bbuf + (size_t)(ks * 128 + quad * 32) * 8;
      short8 bf0 = *(const short8*)(base + lane15 * 8);          // codes ch*32+0..15
      short8 bf1 = *(const short8*)(base + (16 + lane15) * 8);   // codes ch*32+16..31
      acc0a = __builtin_amdgcn_mfma_f32_16x16x32_bf16(aHi0[ks], bf0, acc0a, 0, 0, 0);
      acc0a = __builtin_amdgcn_mfma_f32_16x16x32_bf16(aLo0[ks], bf0, acc0a, 0, 0, 0);
      acc1a = __builtin_amdgcn_mfma_f32_16x16x32_bf16(aHi1[ks], bf0, acc1a, 0, 0, 0);
      acc1a = __builtin_amdgcn_mfma_f32_16x16x32_bf16(aLo1[ks], bf0, acc1a, 0, 0, 0);
      acc0b = __builtin_amdgcn_mfma_f32_16x16x32_bf16(aHi0[ks], bf1, acc0b, 0, 0, 0);
      acc0b = __builtin_amdgcn_mfma_f32_16x16x32_bf16(aLo0[ks], bf1, acc0b, 0, 0, 0);
      acc1b = __builtin_amdgcn_mfma_f32_16x16x32_bf16(aHi1[ks], bf1, acc1b, 0, 0, 0);
      acc1b = __builtin_amdgcn_mfma_f32_16x16x32_bf16(aLo1[ks], bf1, acc1b, 0, 0, 0);
    }
    // scores; per-lane code order ascending: n0 (tile a) then n0+16 (tile b)
    const int n0 = ch * 32 + lane15;
    const float en0 = sNorm[n0];
    const float en1 = sNorm[n0 + 16];
    #pragma unroll
    for (int r = 0; r < 4; ++r) {
      float s = fmaf(-2.0f, acc0a[r], en0);
      if (s < b1[r])      { b2[r] = b1[r]; i2[r] = i1[r]; b1[r] = s; i1[r] = n0; }
      else if (s < b2[r]) { b2[r] = s; i2[r] = n0; }
      s = fmaf(-2.0f, acc1a[r], en0);
      if (s < b1[4+r])      { b2[4+r] = b1[4+r]; i2[4+r] = i1[4+r]; b1[4+r] = s; i1[4+r] = n0; }
      else if (s < b2[4+r]) { b2[4+r] = s; i2[4+r] = n0; }
    }
    #pragma unroll
    for (int r = 0; r < 4; ++r) {
      const int n1 = n0 + 16;
      float s = fmaf(-2.0f, acc0b[r], en1);
      if (s < b1[r])      { b2[r] = b1[r]; i2[r] = i1[r]; b1[r] = s; i1[r] = n1; }
      else if (s < b2[r]) { b2[r] = s; i2[r] = n1; }
      s = fmaf(-2.0f, acc1b[r], en1);
      if (s < b1[4+r])      { b2[4+r] = b1[4+r]; i2[4+r] = i1[4+r]; b1[4+r] = s; i1[4+r] = n1; }
      else if (s < b2[4+r]) { b2[4+r] = s; i2[4+r] = n1; }
    }
    if (ch < 31) __syncthreads();   // drains vmcnt: next buffer staged + all reads done
  }

  // butterfly top-2 merge across the 16 lanes sharing each pixel
  #pragma unroll
  for (int m = 1; m <= 8; m <<= 1) {
    #pragma unroll
    for (int p = 0; p < 8; ++p) {
      float ob1 = __shfl_xor(b1[p], m), ob2 = __shfl_xor(b2[p], m);
      int oi1 = __shfl_xor(i1[p], m), oi2 = __shfl_xor(i2[p], m);
      bool aF = (b1[p] < ob1) || (b1[p] == ob1 && i1[p] < oi1);
      float w1 = aF ? b1[p] : ob1;  int wi1 = aF ? i1[p] : oi1;
      float lf = aF ? ob1 : b1[p];  int lfi = aF ? oi1 : i1[p];
      float ws = aF ? b2[p] : ob2;  int wsi = aF ? i2[p] : oi2;
      bool sF = (ws < lf) || (ws == lf && wsi < lfi);
      b1[p] = w1; i1[p] = wi1;
      b2[p] = sF ? ws : lf; i2[p] = sF ? wsi : lfi;
    }
  }
  if (lane15 == 0) {
    #pragma unroll
    for (int p = 0; p < 8; ++p) {
      const int tl = p >> 2, r = p & 3;
      const int pix = pix0 + w * 32 + tl * 16 + quad * 4 + r;
      if (b2[p] - b1[p] >= MARGIN_S) {
        selIdx[pix] = i1[p];
        out[OUT_IDX + pix] = (float)i1[p];
      } else {
        int pos = atomicAdd(count, 1);
        worklist[pos] = pix;
      }
    }
  }
}

// ---------------- k_refine v3: LDS mini-GEMM exact re-scan ------------------
// 1024 blocks x 256 threads. Group = RG(8) pixels; wave w covers pixels
// 2w,2w+1 (one per half-wave); lane&31 owns one code of each RTILE(32) tile.
// Codebook tile staged coalesced into LDS (rows padded to 260 floats).
// Dot = validated sequential ascending-c fp32 FMA chain, operands from LDS.
__launch_bounds__(256, 2)
__global__ void k_refine(const float* __restrict__ lat, const float* __restrict__ emb,
                         const float* __restrict__ enormQ,
                         const int* __restrict__ count, const int* __restrict__ worklist,
                         int* __restrict__ selIdx, float* __restrict__ out) {
  __shared__ __align__(16) float sE[RTILE * RSTRIDE];   // 33,280 B
  __shared__ __align__(16) float sX[RG * RSTRIDE];      // 8,320 B
  __shared__ float sSx[RG];
  const int t = threadIdx.x;
  const int cnt = *count;
  if (cnt == 0) return;
  const int ngroups = (cnt + RG - 1) / RG;
  const int w = t >> 6, lane = t & 63;
  const int sub = lane >> 5;           // half-wave: 0 or 1
  const int kLane = lane & 31;         // code slot within tile
  const int pixSlot = w * 2 + sub;     // 0..7

  for (int g = blockIdx.x; g < ngroups; g += gridDim.x) {
    // ---- stage RG pixels' latents (tail pixels clamped, never written) ----
    {
      const int p = t >> 5, c0 = t & 31;    // 32 threads per pixel
      int wi = g * RG + p; if (wi >= cnt) wi = cnt - 1;
      const int pix = worklist[wi];
      const float* latB = lat + (size_t)(pix >> 10) * BSTRIDE + (pix & 1023);
      #pragma unroll
      for (int i = 0; i < 8; ++i) {
        int c = c0 + 32 * i;
        sX[p * RSTRIDE + c] = latB[(size_t)c * 1024];
      }
    }
    __syncthreads();
    // ---- per-pixel numpy-pairwise Sx (threads 0..RG-1) ----
    if (t < RG) {
      const float* a0 = sX + t * RSTRIDE;
      float blk[2];
      #pragma unroll
      for (int h = 0; h < 2; ++h) {
        const float* a = a0 + h * 128;
        float r[8];
        #pragma unroll
        for (int j = 0; j < 8; ++j) r[j] = __fmul_rn(a[j], a[j]);
        for (int i = 8; i < 128; i += 8)
          #pragma unroll
          for (int j = 0; j < 8; ++j) r[j] = __fadd_rn(r[j], __fmul_rn(a[i+j], a[i+j]));
        blk[h] = __fadd_rn(__fadd_rn(__fadd_rn(r[0], r[1]), __fadd_rn(r[2], r[3])),
                           __fadd_rn(__fadd_rn(r[4], r[5]), __fadd_rn(r[6], r[7])));
      }
      sSx[t] = __fadd_rn(blk[0], blk[1]);
    }

    float best = INFINITY; int bi = 0x7fffffff;
    const float* xrow = sX + pixSlot * RSTRIDE;
    for (int tile = 0; tile < 32; ++tile) {
      __syncthreads();   // prev-tile reads done (also orders sSx writes)
      // stage tile: 32 rows x 256 floats (64 float4/row; 8 threads/row x 8)
      {
        const int r = t >> 3, q0 = t & 7;   // 8 threads per row
        const float* src = emb + (size_t)(tile * RTILE + r) * 256;
        #pragma unroll
        for (int i = 0; i < 8; ++i) {
          int q = q0 + 8 * i;
          *(float4*)(sE + r * RSTRIDE + q * 4) = *(const float4*)(src + q * 4);
        }
      }
      __syncthreads();
      // exact ascending-c chain from LDS
      const float* erow = sE + kLane * RSTRIDE;
      float d = 0.f;
      for (int c = 0; c < 256; c += 4) {
        float4 xv = *(const float4*)(xrow + c);
        float4 ev = *(const float4*)(erow + c);
        d = fmaf(xv.x, ev.x, d); d = fmaf(xv.y, ev.y, d);
        d = fmaf(xv.z, ev.z, d); d = fmaf(xv.w, ev.w, d);
      }
      const int k = tile * RTILE + kLane;
      float dq = __fsub_rn(__fadd_rn(sSx[pixSlot], enormQ[k]), __fmul_rn(2.0f, d));
      if (dq < best) { best = dq; bi = k; }   // ascending k per lane
    }
    // lexicographic reduce within each half-wave (pre-update read semantics
    // keep the tree correct; polluted upper lanes are never re-consumed)
    for (int off = 16; off > 0; off >>= 1) {
      float ob = __shfl_down(best, off);
      int oi = __shfl_down(bi, off);
      if (ob < best || (ob == best && oi < bi)) { best = ob; bi = oi; }
    }
    if (kLane == 0) {
      const int wi = g * RG + pixSlot;
      if (wi < cnt) {
        const int pix = worklist[wi];
        selIdx[pix] = bi;
        out[OUT_IDX + pix] = (float)bi;
      }
    }
    __syncthreads();   // sX/sSx stable until all waves finish the group
  }
}

// ---------------- k_gather: gather + straight-through + loss ----------------
__global__ void k_gather(const float* __restrict__ lat, const float* __restrict__ emb,
                         const int* __restrict__ selIdx,
                         float* __restrict__ out, double* __restrict__ lossAcc) {
  __shared__ int sIdx[64];
  const int t = threadIdx.x;
  const int pix0 = blockIdx.x * 64;
  const int b = pix0 >> 10;
  const int hw0 = pix0 & 1023;
  const float* latBase = lat + (size_t)b * BSTRIDE + hw0;

  if (t < 64) sIdx[t] = selIdx[pix0 + t];
  __syncthreads();

  const int cSub = t >> 4;
  const int p4 = (t & 15) * 4;
  const int k0 = sIdx[p4], k1 = sIdx[p4+1], k2 = sIdx[p4+2], k3 = sIdx[p4+3];
  double lsum = 0.0;
  #pragma unroll 4
  for (int i = 0; i < 16; ++i) {
    int c = i * 16 + cSub;
    float4 l = *(const float4*)(latBase + (size_t)c * 1024 + p4);
    float q0 = emb[k0 * DIM + c], q1 = emb[k1 * DIM + c],
          q2 = emb[k2 * DIM + c], q3 = emb[k3 * DIM + c];
    float d0 = q0 - l.x, d1 = q1 - l.y, d2 = q2 - l.z, d3 = q3 - l.w;
    float4 o; o.x = l.x + d0; o.y = l.y + d1; o.z = l.z + d2; o.w = l.w + d3;
    *(float4*)(out + (size_t)b * BSTRIDE + (size_t)c * 1024 + hw0 + p4) = o;
    lsum += (double)d0*d0 + (double)d1*d1 + (double)d2*d2 + (double)d3*d3;
  }
  for (int off = 32; off > 0; off >>= 1) lsum += __shfl_down(lsum, off);
  if ((t & 63) == 0) atomicAdd(lossAcc, lsum);
}

__global__ void k_loss(const double* __restrict__ lossAcc, float* __restrict__ out) {
  double m = *lossAcc * (1.0 / 16777216.0);
  out[OUT_LOSS] = (float)(1.25 * m);
}

extern "C" void kernel_launch(void* const* d_in, const int* in_sizes, int n_in,
                              void* d_out, int out_size, void* d_ws, size_t ws_size,
                              hipStream_t stream) {
  const float* lat = (const float*)d_in[0];
  const float* emb = (const float*)d_in[1];
  float* out = (float*)d_out;
  char* ws = (char*)d_ws;
  double* lossAcc = (double*)(ws + WS_LOSS);
  int* count = (int*)(ws + WS_COUNT);
  float* enormQ = (float*)(ws + WS_ENORM);
  unsigned short* embHi = (unsigned short*)(ws + WS_EMBH);
  int* selIdx = (int*)(ws + WS_SEL);
  int* worklist = (int*)(ws + WS_WL);

  k_prep<<<dim3(16), dim3(64), 0, stream>>>(emb, enormQ, lossAcc, count);
  k_embconv<<<dim3(256), dim3(256), 0, stream>>>(emb, embHi);
  k_score<<<dim3(512), dim3(256), 0, stream>>>(lat, embHi, enormQ, selIdx, out, count, worklist);
  k_refine<<<dim3(1024), dim3(256), 0, stream>>>(lat, emb, enormQ, count, worklist, selIdx, out);
  k_gather<<<dim3(1024), dim3(256), 0, stream>>>(lat, emb, selIdx, out, lossAcc);
  k_loss<<<dim3(1), dim3(1), 0, stream>>>(lossAcc, out);
}